// Round 1
// baseline (562.119 us; speedup 1.0000x reference)
//
#include <hip/hip_runtime.h>

// Problem constants
#define BB 4
#define CC 128
#define NN 512
#define TT 16
#define HH 4
#define DKK 32
// SCALE = sqrt(DK) = sqrt(32);  1/SCALE:
#define INV_SCALE 0.17677669529663687f

// ---------------------------------------------------------------------------
// Kernel 1: Q/K projection.
// Q[b,t,h,n,d] = sum_c Wq[h*32+d, c] * x[b,c,n,t]   (same for K)
// Layout of Qw/Kw: [B,T,H,N,DK] contiguous.
// Block: (n-group of 4, b). 256 threads: wave og=tid>>6 computes output rows
// og*32..og*32+31 (== head og), point nt=tid&63 -> (n_local, t).
// ---------------------------------------------------------------------------
__global__ __launch_bounds__(256) void k_proj(const float* __restrict__ x,
                                              const float* __restrict__ Wq,
                                              const float* __restrict__ Wk,
                                              float* __restrict__ Qw,
                                              float* __restrict__ Kw) {
  __shared__ float xl[128 * 64];  // [c][nt] 32 KB
  const int b = blockIdx.y;
  const int n0 = blockIdx.x * 4;
  const int tid = threadIdx.x;

  const float* xb = x + (size_t)b * 1048576 + n0 * 16;
  for (int L = tid; L < 8192; L += 256) {
    int c = L >> 6, nt = L & 63;
    xl[L] = xb[c * 8192 + nt];
  }
  __syncthreads();

  const int og = tid >> 6, nt = tid & 63;
  const int nl = nt >> 4, t = nt & 15, n = n0 + nl;

  float qa[32] __attribute__((aligned(16)));
  float ka[32] __attribute__((aligned(16)));
#pragma unroll
  for (int i = 0; i < 32; ++i) { qa[i] = 0.f; ka[i] = 0.f; }

  const float* wq = Wq + og * 32 * 128;
  const float* wk = Wk + og * 32 * 128;

  for (int c4 = 0; c4 < 32; ++c4) {
    const float xv0 = xl[(c4 * 4 + 0) * 64 + nt];
    const float xv1 = xl[(c4 * 4 + 1) * 64 + nt];
    const float xv2 = xl[(c4 * 4 + 2) * 64 + nt];
    const float xv3 = xl[(c4 * 4 + 3) * 64 + nt];
#pragma unroll
    for (int i = 0; i < 32; ++i) {
      float4 w4 = *(const float4*)(wq + i * 128 + c4 * 4);
      qa[i] = fmaf(w4.x, xv0, qa[i]);
      qa[i] = fmaf(w4.y, xv1, qa[i]);
      qa[i] = fmaf(w4.z, xv2, qa[i]);
      qa[i] = fmaf(w4.w, xv3, qa[i]);
      float4 v4 = *(const float4*)(wk + i * 128 + c4 * 4);
      ka[i] = fmaf(v4.x, xv0, ka[i]);
      ka[i] = fmaf(v4.y, xv1, ka[i]);
      ka[i] = fmaf(v4.z, xv2, ka[i]);
      ka[i] = fmaf(v4.w, xv3, ka[i]);
    }
  }

  // store: Qw[b,t,og,n,0..31]
  float* qo = Qw + (size_t)b * 1048576 + t * 65536 + og * 16384 + n * 32;
  float* ko = Kw + (size_t)b * 1048576 + t * 65536 + og * 16384 + n * 32;
#pragma unroll
  for (int k4 = 0; k4 < 8; ++k4) {
    ((float4*)qo)[k4] = ((const float4*)qa)[k4];
    ((float4*)ko)[k4] = ((const float4*)ka)[k4];
  }
}

// ---------------------------------------------------------------------------
// Kernel 2: scores + softmax (no max-subtraction; |logit| <~ 6) + accumulate
// sum over (t,h) of softmax rows into accA[b,n,m] via atomicAdd.
// Block: (n-tile of 32, t, b). Thread: row r=tid>>3, col-group cg=tid&7
// (cols j = chunk*128 + u*8 + cg, u=0..15, chunk=0..3 -> 64 cols/thread).
// ---------------------------------------------------------------------------
__global__ __launch_bounds__(256) void k_scores(const float* __restrict__ Qw,
                                                const float* __restrict__ Kw,
                                                float* __restrict__ accA) {
  __shared__ float Qs[32 * 36];   // padded stride 36 (16B aligned, no conflicts)
  __shared__ float Ks[128 * 36];
  const int b = blockIdx.z, t = blockIdx.y, n0 = blockIdx.x * 32;
  const int tid = threadIdx.x;
  const int r = tid >> 3, cg = tid & 7;

  float acc[64];
#pragma unroll
  for (int v = 0; v < 64; ++v) acc[v] = 0.f;

  const int baseQ = b * 1048576 + t * 65536;

  for (int h = 0; h < 4; ++h) {
    // stage Q tile: 32 rows x 32
    {
      int L = tid * 4;
      int row = L >> 5, d0 = L & 31;
      float4 q4 = *(const float4*)(Qw + baseQ + h * 16384 + (n0 + row) * 32 + d0);
      *(float4*)(Qs + row * 36 + d0) = q4;
    }
    __syncthreads();

    float qreg[32];
#pragma unroll
    for (int d4 = 0; d4 < 8; ++d4) {
      float4 q4 = *(const float4*)(Qs + r * 36 + d4 * 4);
      qreg[d4 * 4 + 0] = q4.x; qreg[d4 * 4 + 1] = q4.y;
      qreg[d4 * 4 + 2] = q4.z; qreg[d4 * 4 + 3] = q4.w;
    }

    float cur[64];
    float rowsum = 0.f;

    for (int chunk = 0; chunk < 4; ++chunk) {
      __syncthreads();  // protect Ks (and Qs on first pass) before overwrite
#pragma unroll
      for (int L = tid * 4; L < 4096; L += 1024) {
        int m = L >> 5, d0 = L & 31;
        float4 k4 = *(const float4*)(Kw + baseQ + h * 16384 + (chunk * 128 + m) * 32 + d0);
        *(float4*)(Ks + m * 36 + d0) = k4;
      }
      __syncthreads();

#pragma unroll
      for (int u = 0; u < 16; ++u) {
        const float* kr = Ks + (u * 8 + cg) * 36;
        float s = 0.f;
#pragma unroll
        for (int d4 = 0; d4 < 8; ++d4) {
          float4 kv = *(const float4*)(kr + d4 * 4);
          s = fmaf(qreg[d4 * 4 + 0], kv.x, s);
          s = fmaf(qreg[d4 * 4 + 1], kv.y, s);
          s = fmaf(qreg[d4 * 4 + 2], kv.z, s);
          s = fmaf(qreg[d4 * 4 + 3], kv.w, s);
        }
        float e = __expf(s * INV_SCALE);
        cur[chunk * 16 + u] = e;
        rowsum += e;
      }
    }

    // row sum across the 8 threads of this row (contiguous 8-lane group)
#pragma unroll
    for (int off = 1; off < 8; off <<= 1) rowsum += __shfl_xor(rowsum, off, 8);
    float inv = 1.0f / rowsum;
#pragma unroll
    for (int v = 0; v < 64; ++v) acc[v] = fmaf(cur[v], inv, acc[v]);
  }

  float* arow = accA + (size_t)(b * 512 + n0 + r) * 512;
#pragma unroll
  for (int v = 0; v < 64; ++v) {
    int j = (v >> 4) * 128 + (v & 15) * 8 + cg;
    atomicAdd(arow + j, acc[v]);
  }
}

// ---------------------------------------------------------------------------
// Block reductions (256 threads = 4 waves)
// ---------------------------------------------------------------------------
__device__ __forceinline__ float blk_max(float v, float* red, int tid) {
#pragma unroll
  for (int off = 32; off > 0; off >>= 1) v = fmaxf(v, __shfl_xor(v, off, 64));
  if ((tid & 63) == 0) red[tid >> 6] = v;
  __syncthreads();
  v = fmaxf(fmaxf(red[0], red[1]), fmaxf(red[2], red[3]));
  __syncthreads();
  return v;
}
__device__ __forceinline__ float blk_sum(float v, float* red, int tid) {
#pragma unroll
  for (int off = 32; off > 0; off >>= 1) v += __shfl_xor(v, off, 64);
  if ((tid & 63) == 0) red[tid >> 6] = v;
  __syncthreads();
  v = (red[0] + red[1]) + (red[2] + red[3]);
  __syncthreads();
  return v;
}

// Kernel 3a: att_struct = softmax(structural, axis=-1). One block per row.
__global__ __launch_bounds__(256) void k_struct(const float* __restrict__ S,
                                                float* __restrict__ st) {
  __shared__ float red[4];
  const int i = blockIdx.x, tid = threadIdx.x;
  float s0 = S[i * 512 + tid], s1 = S[i * 512 + tid + 256];
  float m = blk_max(fmaxf(s0, s1), red, tid);
  float e0 = __expf(s0 - m), e1 = __expf(s1 - m);
  float sum = blk_sum(e0 + e1, red, tid);
  float inv = 1.0f / sum;
  st[i * 512 + tid] = e0 * inv;
  st[i * 512 + tid + 256] = e1 * inv;
}

// Kernel 3b: fused = softmax_j( w0*0.5*(an[i,j]+an[j,i]) + w1*0.5*(st[i,j]+st[j,i]) + b )
// an = accA/64 (mean over t,h). One block per (i, b).
__global__ __launch_bounds__(256) void k_fused(const float* __restrict__ accA,
                                               const float* __restrict__ st,
                                               const float* __restrict__ fw,
                                               const float* __restrict__ fb,
                                               float* __restrict__ fused) {
  __shared__ float red[4];
  const int i = blockIdx.x, b = blockIdx.y, tid = threadIdx.x;
  const float w0s = fw[0] * (0.5f / 64.f);
  const float w1s = fw[1] * 0.5f;
  const float bias = fb[0];
  const float* A = accA + (size_t)b * 262144;
  const int j1 = tid + 256;
  float l0 = fmaf(w0s, A[i * 512 + tid] + A[tid * 512 + i],
                  fmaf(w1s, st[i * 512 + tid] + st[tid * 512 + i], bias));
  float l1 = fmaf(w0s, A[i * 512 + j1] + A[j1 * 512 + i],
                  fmaf(w1s, st[i * 512 + j1] + st[j1 * 512 + i], bias));
  float m = blk_max(fmaxf(l0, l1), red, tid);
  float e0 = __expf(l0 - m), e1 = __expf(l1 - m);
  float sum = blk_sum(e0 + e1, red, tid);
  float inv = 1.0f / sum;
  fused[(size_t)b * 262144 + i * 512 + tid] = e0 * inv;
  fused[(size_t)b * 262144 + i * 512 + j1] = e1 * inv;
}

// ---------------------------------------------------------------------------
// Kernel 4: out[b,c,i,t] = sum_j fused[b,i,j] * x[b,c,j,t]
// Block: (c-tile of 4, i-tile of 32, b). Thread: i_l=tid>>3, c_l=(tid&7)>>1,
// t-half th=tid&1. 8 outputs/thread (one t-octet).
// ---------------------------------------------------------------------------
__global__ __launch_bounds__(256) void k_agg(const float* __restrict__ fused,
                                             const float* __restrict__ x,
                                             float* __restrict__ out) {
  __shared__ float fl[32 * 68];       // fused tile, padded stride 68
  __shared__ float xs[64 * 4 * 16];   // [j][c][t]
  const int cb = blockIdx.x, ib = blockIdx.y, b = blockIdx.z;
  const int c0 = cb * 4, i0 = ib * 32;
  const int tid = threadIdx.x;
  const int i_l = tid >> 3, rr = tid & 7, c_l = rr >> 1, th = rr & 1;

  float acc[8] __attribute__((aligned(16)));
#pragma unroll
  for (int k = 0; k < 8; ++k) acc[k] = 0.f;

  for (int jc = 0; jc < 8; ++jc) {
    __syncthreads();
    // stage fused rows: 32 x 64
#pragma unroll
    for (int LL = tid * 4; LL < 2048; LL += 1024) {
      int row = LL >> 6, jj = LL & 63;
      float4 f4 = *(const float4*)(fused + (size_t)b * 262144 + (i0 + row) * 512 + jc * 64 + jj);
      *(float4*)(fl + row * 68 + jj) = f4;
    }
    // stage x: 4 c x 64 j x 16 t  -> xs[j][c][t]
#pragma unroll
    for (int LL = tid * 4; LL < 4096; LL += 1024) {
      int c = LL >> 10, j = (LL >> 4) & 63, t0 = LL & 15;
      float4 x4 = *(const float4*)(x + (size_t)b * 1048576 + (c0 + c) * 8192 + (jc * 64 + j) * 16 + t0);
      *(float4*)(xs + (j * 4 + c) * 16 + t0) = x4;
    }
    __syncthreads();

#pragma unroll
    for (int j = 0; j < 64; ++j) {
      float f = fl[i_l * 68 + j];
      const float4* xp = (const float4*)(xs + (j * 4 + c_l) * 16 + th * 8);
      float4 a = xp[0], d = xp[1];
      acc[0] = fmaf(f, a.x, acc[0]); acc[1] = fmaf(f, a.y, acc[1]);
      acc[2] = fmaf(f, a.z, acc[2]); acc[3] = fmaf(f, a.w, acc[3]);
      acc[4] = fmaf(f, d.x, acc[4]); acc[5] = fmaf(f, d.y, acc[5]);
      acc[6] = fmaf(f, d.z, acc[6]); acc[7] = fmaf(f, d.w, acc[7]);
    }
  }

  float* op = out + (size_t)b * 1048576 + (c0 + c_l) * 8192 + (i0 + i_l) * 16 + th * 8;
  ((float4*)op)[0] = *(const float4*)(acc);
  ((float4*)op)[1] = *(const float4*)(acc + 4);
}

// ---------------------------------------------------------------------------
extern "C" void kernel_launch(void* const* d_in, const int* in_sizes, int n_in,
                              void* d_out, int out_size, void* d_ws, size_t ws_size,
                              hipStream_t stream) {
  const float* x  = (const float*)d_in[0];
  const float* Wq = (const float*)d_in[1];
  const float* Wk = (const float*)d_in[2];
  const float* S  = (const float*)d_in[3];
  const float* fw = (const float*)d_in[4];
  const float* fb = (const float*)d_in[5];
  float* out = (float*)d_out;
  float* ws  = (float*)d_ws;

  // workspace layout (floats): Qw 4M | Kw 4M | accA 1M | st 256K | fused 1M
  float* Qw    = ws;
  float* Kw    = ws + 4194304;
  float* accA  = ws + 8388608;
  float* st    = ws + 9437184;
  float* fused = ws + 9699328;

  hipMemsetAsync(accA, 0, 1048576 * sizeof(float), stream);

  k_proj  <<<dim3(128, 4),     256, 0, stream>>>(x, Wq, Wk, Qw, Kw);
  k_scores<<<dim3(16, 16, 4),  256, 0, stream>>>(Qw, Kw, accA);
  k_struct<<<dim3(512),        256, 0, stream>>>(S, st);
  k_fused <<<dim3(512, 4),     256, 0, stream>>>(accA, st, fw, fb, fused);
  k_agg   <<<dim3(32, 16, 4),  256, 0, stream>>>(fused, x, out);
}

// Round 2
// 371.746 us; speedup vs baseline: 1.5121x; 1.5121x over previous
//
#include <hip/hip_runtime.h>

// Problem constants
#define BB 4
#define CC 128
#define NN 512
#define TT 16
#define HH 4
#define DKK 32
// SCALE = sqrt(DK) = sqrt(32);  1/SCALE:
#define INV_SCALE 0.17677669529663687f

typedef __attribute__((ext_vector_type(8))) short bf16x8;
typedef __attribute__((ext_vector_type(4))) float f32x4;

// pack two floats to bf16 pair (RNE)
__device__ __forceinline__ unsigned int pk2bf(float a, float b) {
  unsigned int ua = __float_as_uint(a);
  ua = (ua + 0x7FFFu + ((ua >> 16) & 1u)) >> 16;
  unsigned int ub = __float_as_uint(b);
  ub = (ub + 0x7FFFu + ((ub >> 16) & 1u)) >> 16;
  return ua | (ub << 16);
}

// ---------------------------------------------------------------------------
// Kernel 1: Q/K projection -> bf16.
// Qb[b,t,h,n,d] = sum_c Wq[h*32+d, c] * x[b,c,n,t]   (same for K)
// ---------------------------------------------------------------------------
__global__ __launch_bounds__(256) void k_proj(const float* __restrict__ x,
                                              const float* __restrict__ Wq,
                                              const float* __restrict__ Wk,
                                              ushort* __restrict__ Qb,
                                              ushort* __restrict__ Kb) {
  __shared__ float xl[128 * 64];  // [c][nt] 32 KB
  const int b = blockIdx.y;
  const int n0 = blockIdx.x * 4;
  const int tid = threadIdx.x;

  const float* xb = x + (size_t)b * 1048576 + n0 * 16;
  for (int L = tid; L < 8192; L += 256) {
    int c = L >> 6, nt = L & 63;
    xl[L] = xb[c * 8192 + nt];
  }
  __syncthreads();

  const int og = tid >> 6, nt = tid & 63;
  const int nl = nt >> 4, t = nt & 15, n = n0 + nl;

  float qa[32];
  float ka[32];
#pragma unroll
  for (int i = 0; i < 32; ++i) { qa[i] = 0.f; ka[i] = 0.f; }

  const float* wq = Wq + og * 32 * 128;
  const float* wk = Wk + og * 32 * 128;

  for (int c4 = 0; c4 < 32; ++c4) {
    const float xv0 = xl[(c4 * 4 + 0) * 64 + nt];
    const float xv1 = xl[(c4 * 4 + 1) * 64 + nt];
    const float xv2 = xl[(c4 * 4 + 2) * 64 + nt];
    const float xv3 = xl[(c4 * 4 + 3) * 64 + nt];
#pragma unroll
    for (int i = 0; i < 32; ++i) {
      float4 w4 = *(const float4*)(wq + i * 128 + c4 * 4);
      qa[i] = fmaf(w4.x, xv0, qa[i]);
      qa[i] = fmaf(w4.y, xv1, qa[i]);
      qa[i] = fmaf(w4.z, xv2, qa[i]);
      qa[i] = fmaf(w4.w, xv3, qa[i]);
      float4 v4 = *(const float4*)(wk + i * 128 + c4 * 4);
      ka[i] = fmaf(v4.x, xv0, ka[i]);
      ka[i] = fmaf(v4.y, xv1, ka[i]);
      ka[i] = fmaf(v4.z, xv2, ka[i]);
      ka[i] = fmaf(v4.w, xv3, ka[i]);
    }
  }

  uint4 qp[4], kp[4];
#pragma unroll
  for (int g = 0; g < 4; ++g) {
    qp[g].x = pk2bf(qa[g * 8 + 0], qa[g * 8 + 1]);
    qp[g].y = pk2bf(qa[g * 8 + 2], qa[g * 8 + 3]);
    qp[g].z = pk2bf(qa[g * 8 + 4], qa[g * 8 + 5]);
    qp[g].w = pk2bf(qa[g * 8 + 6], qa[g * 8 + 7]);
    kp[g].x = pk2bf(ka[g * 8 + 0], ka[g * 8 + 1]);
    kp[g].y = pk2bf(ka[g * 8 + 2], ka[g * 8 + 3]);
    kp[g].z = pk2bf(ka[g * 8 + 4], ka[g * 8 + 5]);
    kp[g].w = pk2bf(ka[g * 8 + 6], ka[g * 8 + 7]);
  }

  const size_t base = (size_t)b * 1048576 + t * 65536 + og * 16384 + (size_t)n * 32;
  uint4* qo = (uint4*)(Qb + base);
  uint4* ko = (uint4*)(Kb + base);
#pragma unroll
  for (int g = 0; g < 4; ++g) { qo[g] = qp[g]; ko[g] = kp[g]; }
}

// ---------------------------------------------------------------------------
// Kernel 2: MFMA scores + softmax + partial mean over (t,h).
// Grid (32 strips, 8 groups, 4 b), block = 64 threads (one wave).
// Wave owns rows n0=strip*16 .. +16, all 512 cols, loops 8 (t,h) pairs.
// Per pair: 32x mfma_f32_16x16x32_bf16 -> exp -> LDS strip; 16-lane rowsum
// reduce; normalized accumulate into 128 VGPRs. Partial out: bf16.
// ---------------------------------------------------------------------------
__global__ __launch_bounds__(64) void k_scores(const ushort* __restrict__ Qb,
                                               const ushort* __restrict__ Kb,
                                               ushort* __restrict__ part) {
  __shared__ float SH[16 * 516];  // 33 KB, stride 516: 2-way banks (free)
  const int strip = blockIdx.x, g = blockIdx.y, b = blockIdx.z;
  const int lane = threadIdx.x;
  const int lm = lane & 15, quad = lane >> 4;
  const int n0 = strip * 16;
  const int d0 = quad * 8;
  const int r2 = lane >> 2, cb2 = (lane & 3) * 4;
  const int rsel = r2 & 3;

  float acc[128];
#pragma unroll
  for (int i = 0; i < 128; ++i) acc[i] = 0.f;

  for (int pi = 0; pi < 8; ++pi) {
    const int p = (g << 3) + pi, t = p >> 2, h = p & 3;
    const size_t base = (size_t)(((b * 16 + t) * 4 + h)) * 16384;
    bf16x8 afrag = *(const bf16x8*)(Qb + base + (size_t)(n0 + lm) * 32 + d0);
    float rp0 = 0.f, rp1 = 0.f, rp2 = 0.f, rp3 = 0.f;
    bf16x8 bfrag = *(const bf16x8*)(Kb + base + (size_t)lm * 32 + d0);
#pragma unroll 4
    for (int ct = 0; ct < 32; ++ct) {
      bf16x8 curb = bfrag;
      if (ct < 31)
        bfrag = *(const bf16x8*)(Kb + base + (size_t)((ct + 1) * 16 + lm) * 32 + d0);
      f32x4 z = {0.f, 0.f, 0.f, 0.f};
      f32x4 dv = __builtin_amdgcn_mfma_f32_16x16x32_bf16(afrag, curb, z, 0, 0, 0);
      float e0 = __expf(dv[0] * INV_SCALE);
      float e1 = __expf(dv[1] * INV_SCALE);
      float e2 = __expf(dv[2] * INV_SCALE);
      float e3 = __expf(dv[3] * INV_SCALE);
      float* sp = SH + (quad * 4) * 516 + ct * 16 + lm;
      sp[0] = e0; sp[516] = e1; sp[1032] = e2; sp[1548] = e3;
      rp0 += e0; rp1 += e1; rp2 += e2; rp3 += e3;
    }
    // rowsum: reduce across the 16 lanes sharing this quad
#pragma unroll
    for (int m = 1; m < 16; m <<= 1) {
      rp0 += __shfl_xor(rp0, m);
      rp1 += __shfl_xor(rp1, m);
      rp2 += __shfl_xor(rp2, m);
      rp3 += __shfl_xor(rp3, m);
    }
    // lane's pass-2 row is r2 = quad*4 + rsel -> rowsum is its own rp[rsel]
    float rs = (rsel == 0) ? rp0 : (rsel == 1) ? rp1 : (rsel == 2) ? rp2 : rp3;
    float inv = 1.0f / rs;
    __builtin_amdgcn_s_waitcnt(0xC07F);  // lgkmcnt(0): LDS writes -> reads
#pragma unroll
    for (int k = 0; k < 32; ++k) {
      f32x4 v = *(const f32x4*)(SH + r2 * 516 + cb2 + k * 16);
      acc[k * 4 + 0] = fmaf(v[0], inv, acc[k * 4 + 0]);
      acc[k * 4 + 1] = fmaf(v[1], inv, acc[k * 4 + 1]);
      acc[k * 4 + 2] = fmaf(v[2], inv, acc[k * 4 + 2]);
      acc[k * 4 + 3] = fmaf(v[3], inv, acc[k * 4 + 3]);
    }
  }

  ushort* po = part + ((size_t)((g * 4 + b) * 512 + n0 + r2)) * 512 + cb2;
#pragma unroll
  for (int k = 0; k < 32; ++k) {
    uint2 u;
    u.x = pk2bf(acc[k * 4 + 0], acc[k * 4 + 1]);
    u.y = pk2bf(acc[k * 4 + 2], acc[k * 4 + 3]);
    *(uint2*)(po + k * 16) = u;
  }
}

// ---------------------------------------------------------------------------
// Kernel 2b: reduce 8 bf16 partials -> accA fp32
// ---------------------------------------------------------------------------
__global__ __launch_bounds__(256) void k_reduce(const ushort* __restrict__ part,
                                                float* __restrict__ accA) {
  const int gid = blockIdx.x * 256 + threadIdx.x;
  const size_t idx = (size_t)gid * 4;
  float s0 = 0.f, s1 = 0.f, s2 = 0.f, s3 = 0.f;
#pragma unroll
  for (int g = 0; g < 8; ++g) {
    ushort4 v = *(const ushort4*)(part + (size_t)g * 1048576 + idx);
    s0 += __uint_as_float((unsigned int)v.x << 16);
    s1 += __uint_as_float((unsigned int)v.y << 16);
    s2 += __uint_as_float((unsigned int)v.z << 16);
    s3 += __uint_as_float((unsigned int)v.w << 16);
  }
  float4 o = make_float4(s0, s1, s2, s3);
  *(float4*)(accA + idx) = o;
}

// ---------------------------------------------------------------------------
// Block reductions (256 threads = 4 waves)
// ---------------------------------------------------------------------------
__device__ __forceinline__ float blk_max(float v, float* red, int tid) {
#pragma unroll
  for (int off = 32; off > 0; off >>= 1) v = fmaxf(v, __shfl_xor(v, off, 64));
  if ((tid & 63) == 0) red[tid >> 6] = v;
  __syncthreads();
  v = fmaxf(fmaxf(red[0], red[1]), fmaxf(red[2], red[3]));
  __syncthreads();
  return v;
}
__device__ __forceinline__ float blk_sum(float v, float* red, int tid) {
#pragma unroll
  for (int off = 32; off > 0; off >>= 1) v += __shfl_xor(v, off, 64);
  if ((tid & 63) == 0) red[tid >> 6] = v;
  __syncthreads();
  v = (red[0] + red[1]) + (red[2] + red[3]);
  __syncthreads();
  return v;
}

// Kernel 3a: att_struct = softmax(structural, axis=-1). One block per row.
__global__ __launch_bounds__(256) void k_struct(const float* __restrict__ S,
                                                float* __restrict__ st) {
  __shared__ float red[4];
  const int i = blockIdx.x, tid = threadIdx.x;
  float s0 = S[i * 512 + tid], s1 = S[i * 512 + tid + 256];
  float m = blk_max(fmaxf(s0, s1), red, tid);
  float e0 = __expf(s0 - m), e1 = __expf(s1 - m);
  float sum = blk_sum(e0 + e1, red, tid);
  float inv = 1.0f / sum;
  st[i * 512 + tid] = e0 * inv;
  st[i * 512 + tid + 256] = e1 * inv;
}

// Kernel 3b: fused = softmax_j( w0*0.5*(an[i,j]+an[j,i]) + w1*0.5*(st[i,j]+st[j,i]) + b )
__global__ __launch_bounds__(256) void k_fused(const float* __restrict__ accA,
                                               const float* __restrict__ st,
                                               const float* __restrict__ fw,
                                               const float* __restrict__ fb,
                                               float* __restrict__ fused) {
  __shared__ float red[4];
  const int i = blockIdx.x, b = blockIdx.y, tid = threadIdx.x;
  const float w0s = fw[0] * (0.5f / 64.f);
  const float w1s = fw[1] * 0.5f;
  const float bias = fb[0];
  const float* A = accA + (size_t)b * 262144;
  const int j1 = tid + 256;
  float l0 = fmaf(w0s, A[i * 512 + tid] + A[tid * 512 + i],
                  fmaf(w1s, st[i * 512 + tid] + st[tid * 512 + i], bias));
  float l1 = fmaf(w0s, A[i * 512 + j1] + A[j1 * 512 + i],
                  fmaf(w1s, st[i * 512 + j1] + st[j1 * 512 + i], bias));
  float m = blk_max(fmaxf(l0, l1), red, tid);
  float e0 = __expf(l0 - m), e1 = __expf(l1 - m);
  float sum = blk_sum(e0 + e1, red, tid);
  float inv = 1.0f / sum;
  fused[(size_t)b * 262144 + i * 512 + tid] = e0 * inv;
  fused[(size_t)b * 262144 + i * 512 + j1] = e1 * inv;
}

// ---------------------------------------------------------------------------
// Kernel 4: out[b,c,i,t] = sum_j fused[b,i,j] * x[b,c,j,t]
// ---------------------------------------------------------------------------
__global__ __launch_bounds__(256) void k_agg(const float* __restrict__ fused,
                                             const float* __restrict__ x,
                                             float* __restrict__ out) {
  __shared__ float fl[32 * 68];       // fused tile, padded stride 68
  __shared__ float xs[64 * 4 * 16];   // [j][c][t]
  const int cb = blockIdx.x, ib = blockIdx.y, b = blockIdx.z;
  const int c0 = cb * 4, i0 = ib * 32;
  const int tid = threadIdx.x;
  const int i_l = tid >> 3, rr = tid & 7, c_l = rr >> 1, th = rr & 1;

  float acc[8] __attribute__((aligned(16)));
#pragma unroll
  for (int k = 0; k < 8; ++k) acc[k] = 0.f;

  for (int jc = 0; jc < 8; ++jc) {
    __syncthreads();
#pragma unroll
    for (int LL = tid * 4; LL < 2048; LL += 1024) {
      int row = LL >> 6, jj = LL & 63;
      float4 f4 = *(const float4*)(fused + (size_t)b * 262144 + (i0 + row) * 512 + jc * 64 + jj);
      *(float4*)(fl + row * 68 + jj) = f4;
    }
#pragma unroll
    for (int LL = tid * 4; LL < 4096; LL += 1024) {
      int c = LL >> 10, j = (LL >> 4) & 63, t0 = LL & 15;
      float4 x4 = *(const float4*)(x + (size_t)b * 1048576 + (c0 + c) * 8192 + (jc * 64 + j) * 16 + t0);
      *(float4*)(xs + (j * 4 + c) * 16 + t0) = x4;
    }
    __syncthreads();

#pragma unroll
    for (int j = 0; j < 64; ++j) {
      float f = fl[i_l * 68 + j];
      const float4* xp = (const float4*)(xs + (j * 4 + c_l) * 16 + th * 8);
      float4 a = xp[0], d = xp[1];
      acc[0] = fmaf(f, a.x, acc[0]); acc[1] = fmaf(f, a.y, acc[1]);
      acc[2] = fmaf(f, a.z, acc[2]); acc[3] = fmaf(f, a.w, acc[3]);
      acc[4] = fmaf(f, d.x, acc[4]); acc[5] = fmaf(f, d.y, acc[5]);
      acc[6] = fmaf(f, d.z, acc[6]); acc[7] = fmaf(f, d.w, acc[7]);
    }
  }

  float* op = out + (size_t)b * 1048576 + (c0 + c_l) * 8192 + (i0 + i_l) * 16 + th * 8;
  ((float4*)op)[0] = *(const float4*)(acc);
  ((float4*)op)[1] = *(const float4*)(acc + 4);
}

// ---------------------------------------------------------------------------
extern "C" void kernel_launch(void* const* d_in, const int* in_sizes, int n_in,
                              void* d_out, int out_size, void* d_ws, size_t ws_size,
                              hipStream_t stream) {
  const float* x  = (const float*)d_in[0];
  const float* Wq = (const float*)d_in[1];
  const float* Wk = (const float*)d_in[2];
  const float* S  = (const float*)d_in[3];
  const float* fw = (const float*)d_in[4];
  const float* fb = (const float*)d_in[5];
  float* out = (float*)d_out;

  // workspace: Qb 8MB | Kb 8MB | part 16MB | accA 4MB | st 1MB | fused 4MB = 41MB
  ushort* Qb   = (ushort*)d_ws;
  ushort* Kb   = Qb + 4194304;
  ushort* part = Kb + 4194304;
  float* accA  = (float*)(part + 8388608);
  float* st    = accA + 1048576;
  float* fused = st + 262144;

  k_proj  <<<dim3(128, 4),    256, 0, stream>>>(x, Wq, Wk, Qb, Kb);
  k_scores<<<dim3(32, 8, 4),   64, 0, stream>>>(Qb, Kb, part);
  k_struct<<<dim3(512),       256, 0, stream>>>(S, st);
  k_reduce<<<dim3(1024),      256, 0, stream>>>(part, accA);
  k_fused <<<dim3(512, 4),    256, 0, stream>>>(accA, st, fw, fb, fused);
  k_agg   <<<dim3(32, 16, 4), 256, 0, stream>>>(fused, x, out);
}

// Round 3
// 244.351 us; speedup vs baseline: 2.3005x; 1.5214x over previous
//
#include <hip/hip_runtime.h>

// Problem constants
#define BB 4
#define CC 128
#define NN 512
#define TT 16
#define HH 4
#define DKK 32
// SCALE = sqrt(DK) = sqrt(32);  1/SCALE:
#define INV_SCALE 0.17677669529663687f

typedef __attribute__((ext_vector_type(8))) short bf16x8;
typedef __attribute__((ext_vector_type(4))) float f32x4;

// pack two floats to bf16 pair (RNE)
__device__ __forceinline__ unsigned int pk2bf(float a, float b) {
  unsigned int ua = __float_as_uint(a);
  ua = (ua + 0x7FFFu + ((ua >> 16) & 1u)) >> 16;
  unsigned int ub = __float_as_uint(b);
  ub = (ub + 0x7FFFu + ((ub >> 16) & 1u)) >> 16;
  return ua | (ub << 16);
}

// fast pack (round-half-up): v_add x2 + v_perm
__device__ __forceinline__ unsigned int pkfast(float a, float b) {
  unsigned int au = __float_as_uint(a) + 0x8000u;
  unsigned int bu = __float_as_uint(b) + 0x8000u;
  return __builtin_amdgcn_perm(bu, au, 0x07060302u);
}

// ---------------------------------------------------------------------------
// Kernel 0: W -> bf16 (Wq,Wk are 128x128 row-major; rows o, cols c)
// ---------------------------------------------------------------------------
__global__ __launch_bounds__(256) void k_wconv(const float* __restrict__ Wq,
                                               const float* __restrict__ Wk,
                                               ushort* __restrict__ Wqb,
                                               ushort* __restrict__ Wkb) {
  const int gid = blockIdx.x * 256 + threadIdx.x;  // 8192 threads
  const int i = gid * 4;
  const float* src = (i < 16384) ? (Wq + i) : (Wk + i - 16384);
  ushort* dst = (i < 16384) ? (Wqb + i) : (Wkb + i - 16384);
  float4 v = *(const float4*)src;
  uint2 u;
  u.x = pk2bf(v.x, v.y);
  u.y = pk2bf(v.z, v.w);
  *(uint2*)dst = u;
}

// ---------------------------------------------------------------------------
// Kernel 1: MFMA Q/K projection -> bf16.
// Qb[b,t,h,n,d] = sum_c Wq[h*32+d, c] * x[b,c,n,t]   (same for K)
// Block: 4 waves, nt-range of 128 (nt = n*16+t). Wave w owns o-strip w*32.
// A = W rows (bf16 from global), B = x columns (fp32 LDS -> pack bf16).
// ---------------------------------------------------------------------------
__global__ __launch_bounds__(256) void k_proj(const float* __restrict__ x,
                                              const ushort* __restrict__ Wqb,
                                              const ushort* __restrict__ Wkb,
                                              ushort* __restrict__ Qb,
                                              ushort* __restrict__ Kb) {
  __shared__ float xl[128 * 128];  // [c][j] 64 KB
  const int b = blockIdx.y;
  const int nt0 = blockIdx.x * 128;
  const int tid = threadIdx.x;
  const int w = tid >> 6, lane = tid & 63;
  const int lm = lane & 15, quad = lane >> 4;

  // stage x[b][c][nt0+0..127] (coalesced float4)
  const float* xb = x + (size_t)b * 1048576 + nt0;
#pragma unroll
  for (int L = tid * 4; L < 16384; L += 1024) {
    int c = L >> 7, j = L & 127;
    *(float4*)(xl + L) = *(const float4*)(xb + c * 8192 + j);
  }

  // A fragments for this wave's o-strip (o0 = w*32): [ot][kc]
  const int o0 = w * 32;
  bf16x8 aq[2][4], ak[2][4];
#pragma unroll
  for (int ot = 0; ot < 2; ++ot)
#pragma unroll
    for (int kc = 0; kc < 4; ++kc) {
      int off = (o0 + ot * 16 + lm) * 128 + kc * 32 + quad * 8;
      aq[ot][kc] = *(const bf16x8*)(Wqb + off);
      ak[ot][kc] = *(const bf16x8*)(Wkb + off);
    }
  __syncthreads();

  const int nq = nt0 >> 4;  // global n of first tile
#pragma unroll 2
  for (int jt = 0; jt < 8; ++jt) {
    // B fragments: lane elem j -> x[c = kc*32+quad*8+j][nt0 + jt*16 + lm]
    bf16x8 bfr[4];
#pragma unroll
    for (int kc = 0; kc < 4; ++kc) {
      const float* sp = xl + (kc * 32 + quad * 8) * 128 + jt * 16 + lm;
      float f0 = sp[0],   f1 = sp[128], f2 = sp[256], f3 = sp[384];
      float f4 = sp[512], f5 = sp[640], f6 = sp[768], f7 = sp[896];
      uint4 u;
      u.x = pkfast(f0, f1);
      u.y = pkfast(f2, f3);
      u.z = pkfast(f4, f5);
      u.w = pkfast(f6, f7);
      union { uint4 u; bf16x8 v; } cv;
      cv.u = u;
      bfr[kc] = cv.v;
    }

    f32x4 accq0 = {0,0,0,0}, accq1 = {0,0,0,0};
    f32x4 acck0 = {0,0,0,0}, acck1 = {0,0,0,0};
#pragma unroll
    for (int kc = 0; kc < 4; ++kc) {
      accq0 = __builtin_amdgcn_mfma_f32_16x16x32_bf16(aq[0][kc], bfr[kc], accq0, 0, 0, 0);
      accq1 = __builtin_amdgcn_mfma_f32_16x16x32_bf16(aq[1][kc], bfr[kc], accq1, 0, 0, 0);
      acck0 = __builtin_amdgcn_mfma_f32_16x16x32_bf16(ak[0][kc], bfr[kc], acck0, 0, 0, 0);
      acck1 = __builtin_amdgcn_mfma_f32_16x16x32_bf16(ak[1][kc], bfr[kc], acck1, 0, 0, 0);
    }

    // C/D: col (nt local) = lm -> t = lm, n = nq + jt; rows = d0 + quad*4 + reg,
    // h == w. Lane stores 4 contiguous d as bf16 (8B).
    const size_t base = (size_t)b * 1048576 + (size_t)lm * 65536 + w * 16384 +
                        (size_t)(nq + jt) * 32 + quad * 4;
    uint2 uq0, uq1, uk0, uk1;
    uq0.x = pk2bf(accq0[0], accq0[1]); uq0.y = pk2bf(accq0[2], accq0[3]);
    uq1.x = pk2bf(accq1[0], accq1[1]); uq1.y = pk2bf(accq1[2], accq1[3]);
    uk0.x = pk2bf(acck0[0], acck0[1]); uk0.y = pk2bf(acck0[2], acck0[3]);
    uk1.x = pk2bf(acck1[0], acck1[1]); uk1.y = pk2bf(acck1[2], acck1[3]);
    *(uint2*)(Qb + base)      = uq0;
    *(uint2*)(Qb + base + 16) = uq1;
    *(uint2*)(Kb + base)      = uk0;
    *(uint2*)(Kb + base + 16) = uk1;
  }
}

// ---------------------------------------------------------------------------
// Kernel 2: MFMA scores + softmax + partial mean over (t,h).
// Grid (32 strips, 8 groups, 4 b), block = 64 threads (one wave).
// ---------------------------------------------------------------------------
__global__ __launch_bounds__(64) void k_scores(const ushort* __restrict__ Qb,
                                               const ushort* __restrict__ Kb,
                                               ushort* __restrict__ part) {
  __shared__ float SH[16 * 516];  // 33 KB, stride 516: 2-way banks (free)
  const int strip = blockIdx.x, g = blockIdx.y, b = blockIdx.z;
  const int lane = threadIdx.x;
  const int lm = lane & 15, quad = lane >> 4;
  const int n0 = strip * 16;
  const int d0 = quad * 8;
  const int r2 = lane >> 2, cb2 = (lane & 3) * 4;
  const int rsel = r2 & 3;

  float acc[128];
#pragma unroll
  for (int i = 0; i < 128; ++i) acc[i] = 0.f;

  for (int pi = 0; pi < 8; ++pi) {
    const int p = (g << 3) + pi, t = p >> 2, h = p & 3;
    const size_t base = (size_t)(((b * 16 + t) * 4 + h)) * 16384;
    bf16x8 afrag = *(const bf16x8*)(Qb + base + (size_t)(n0 + lm) * 32 + d0);
    float rp0 = 0.f, rp1 = 0.f, rp2 = 0.f, rp3 = 0.f;
    bf16x8 bfrag = *(const bf16x8*)(Kb + base + (size_t)lm * 32 + d0);
#pragma unroll 4
    for (int ct = 0; ct < 32; ++ct) {
      bf16x8 curb = bfrag;
      if (ct < 31)
        bfrag = *(const bf16x8*)(Kb + base + (size_t)((ct + 1) * 16 + lm) * 32 + d0);
      f32x4 z = {0.f, 0.f, 0.f, 0.f};
      f32x4 dv = __builtin_amdgcn_mfma_f32_16x16x32_bf16(afrag, curb, z, 0, 0, 0);
      float e0 = __expf(dv[0] * INV_SCALE);
      float e1 = __expf(dv[1] * INV_SCALE);
      float e2 = __expf(dv[2] * INV_SCALE);
      float e3 = __expf(dv[3] * INV_SCALE);
      float* sp = SH + (quad * 4) * 516 + ct * 16 + lm;
      sp[0] = e0; sp[516] = e1; sp[1032] = e2; sp[1548] = e3;
      rp0 += e0; rp1 += e1; rp2 += e2; rp3 += e3;
    }
#pragma unroll
    for (int m = 1; m < 16; m <<= 1) {
      rp0 += __shfl_xor(rp0, m);
      rp1 += __shfl_xor(rp1, m);
      rp2 += __shfl_xor(rp2, m);
      rp3 += __shfl_xor(rp3, m);
    }
    float rs = (rsel == 0) ? rp0 : (rsel == 1) ? rp1 : (rsel == 2) ? rp2 : rp3;
    float inv = 1.0f / rs;
    __builtin_amdgcn_s_waitcnt(0xC07F);  // lgkmcnt(0): LDS writes -> reads
#pragma unroll
    for (int k = 0; k < 32; ++k) {
      f32x4 v = *(const f32x4*)(SH + r2 * 516 + cb2 + k * 16);
      acc[k * 4 + 0] = fmaf(v[0], inv, acc[k * 4 + 0]);
      acc[k * 4 + 1] = fmaf(v[1], inv, acc[k * 4 + 1]);
      acc[k * 4 + 2] = fmaf(v[2], inv, acc[k * 4 + 2]);
      acc[k * 4 + 3] = fmaf(v[3], inv, acc[k * 4 + 3]);
    }
  }

  ushort* po = part + ((size_t)((g * 4 + b) * 512 + n0 + r2)) * 512 + cb2;
#pragma unroll
  for (int k = 0; k < 32; ++k) {
    uint2 u;
    u.x = pk2bf(acc[k * 4 + 0], acc[k * 4 + 1]);
    u.y = pk2bf(acc[k * 4 + 2], acc[k * 4 + 3]);
    *(uint2*)(po + k * 16) = u;
  }
}

// ---------------------------------------------------------------------------
// Kernel 2b: reduce 8 bf16 partials -> accA fp32
// ---------------------------------------------------------------------------
__global__ __launch_bounds__(256) void k_reduce(const ushort* __restrict__ part,
                                                float* __restrict__ accA) {
  const int gid = blockIdx.x * 256 + threadIdx.x;
  const size_t idx = (size_t)gid * 4;
  float s0 = 0.f, s1 = 0.f, s2 = 0.f, s3 = 0.f;
#pragma unroll
  for (int g = 0; g < 8; ++g) {
    ushort4 v = *(const ushort4*)(part + (size_t)g * 1048576 + idx);
    s0 += __uint_as_float((unsigned int)v.x << 16);
    s1 += __uint_as_float((unsigned int)v.y << 16);
    s2 += __uint_as_float((unsigned int)v.z << 16);
    s3 += __uint_as_float((unsigned int)v.w << 16);
  }
  float4 o = make_float4(s0, s1, s2, s3);
  *(float4*)(accA + idx) = o;
}

// ---------------------------------------------------------------------------
// Block reductions (256 threads = 4 waves)
// ---------------------------------------------------------------------------
__device__ __forceinline__ float blk_max(float v, float* red, int tid) {
#pragma unroll
  for (int off = 32; off > 0; off >>= 1) v = fmaxf(v, __shfl_xor(v, off, 64));
  if ((tid & 63) == 0) red[tid >> 6] = v;
  __syncthreads();
  v = fmaxf(fmaxf(red[0], red[1]), fmaxf(red[2], red[3]));
  __syncthreads();
  return v;
}
__device__ __forceinline__ float blk_sum(float v, float* red, int tid) {
#pragma unroll
  for (int off = 32; off > 0; off >>= 1) v += __shfl_xor(v, off, 64);
  if ((tid & 63) == 0) red[tid >> 6] = v;
  __syncthreads();
  v = (red[0] + red[1]) + (red[2] + red[3]);
  __syncthreads();
  return v;
}

// Kernel 3a: att_struct = softmax(structural, axis=-1). One block per row.
__global__ __launch_bounds__(256) void k_struct(const float* __restrict__ S,
                                                float* __restrict__ st) {
  __shared__ float red[4];
  const int i = blockIdx.x, tid = threadIdx.x;
  float s0 = S[i * 512 + tid], s1 = S[i * 512 + tid + 256];
  float m = blk_max(fmaxf(s0, s1), red, tid);
  float e0 = __expf(s0 - m), e1 = __expf(s1 - m);
  float sum = blk_sum(e0 + e1, red, tid);
  float inv = 1.0f / sum;
  st[i * 512 + tid] = e0 * inv;
  st[i * 512 + tid + 256] = e1 * inv;
}

// Kernel 3b: fused = softmax_j( w0*0.5*(an[i,j]+an[j,i]) + w1*0.5*(st[i,j]+st[j,i]) + b )
__global__ __launch_bounds__(256) void k_fused(const float* __restrict__ accA,
                                               const float* __restrict__ st,
                                               const float* __restrict__ fw,
                                               const float* __restrict__ fb,
                                               float* __restrict__ fused) {
  __shared__ float red[4];
  const int i = blockIdx.x, b = blockIdx.y, tid = threadIdx.x;
  const float w0s = fw[0] * (0.5f / 64.f);
  const float w1s = fw[1] * 0.5f;
  const float bias = fb[0];
  const float* A = accA + (size_t)b * 262144;
  const int j1 = tid + 256;
  float l0 = fmaf(w0s, A[i * 512 + tid] + A[tid * 512 + i],
                  fmaf(w1s, st[i * 512 + tid] + st[tid * 512 + i], bias));
  float l1 = fmaf(w0s, A[i * 512 + j1] + A[j1 * 512 + i],
                  fmaf(w1s, st[i * 512 + j1] + st[j1 * 512 + i], bias));
  float m = blk_max(fmaxf(l0, l1), red, tid);
  float e0 = __expf(l0 - m), e1 = __expf(l1 - m);
  float sum = blk_sum(e0 + e1, red, tid);
  float inv = 1.0f / sum;
  fused[(size_t)b * 262144 + i * 512 + tid] = e0 * inv;
  fused[(size_t)b * 262144 + i * 512 + j1] = e1 * inv;
}

// ---------------------------------------------------------------------------
// Kernel 4: out[b,c,i,t] = sum_j fused[b,i,j] * x[b,c,j,t]
// ---------------------------------------------------------------------------
__global__ __launch_bounds__(256) void k_agg(const float* __restrict__ fused,
                                             const float* __restrict__ x,
                                             float* __restrict__ out) {
  __shared__ float fl[32 * 68];       // fused tile, padded stride 68
  __shared__ float xs[64 * 4 * 16];   // [j][c][t]
  const int cb = blockIdx.x, ib = blockIdx.y, b = blockIdx.z;
  const int c0 = cb * 4, i0 = ib * 32;
  const int tid = threadIdx.x;
  const int i_l = tid >> 3, rr = tid & 7, c_l = rr >> 1, th = rr & 1;

  float acc[8] __attribute__((aligned(16)));
#pragma unroll
  for (int k = 0; k < 8; ++k) acc[k] = 0.f;

  for (int jc = 0; jc < 8; ++jc) {
    __syncthreads();
#pragma unroll
    for (int LL = tid * 4; LL < 2048; LL += 1024) {
      int row = LL >> 6, jj = LL & 63;
      float4 f4 = *(const float4*)(fused + (size_t)b * 262144 + (i0 + row) * 512 + jc * 64 + jj);
      *(float4*)(fl + row * 68 + jj) = f4;
    }
#pragma unroll
    for (int LL = tid * 4; LL < 4096; LL += 1024) {
      int c = LL >> 10, j = (LL >> 4) & 63, t0 = LL & 15;
      float4 x4 = *(const float4*)(x + (size_t)b * 1048576 + (c0 + c) * 8192 + (jc * 64 + j) * 16 + t0);
      *(float4*)(xs + (j * 4 + c) * 16 + t0) = x4;
    }
    __syncthreads();

#pragma unroll
    for (int j = 0; j < 64; ++j) {
      float f = fl[i_l * 68 + j];
      const float4* xp = (const float4*)(xs + (j * 4 + c_l) * 16 + th * 8);
      float4 a = xp[0], d = xp[1];
      acc[0] = fmaf(f, a.x, acc[0]); acc[1] = fmaf(f, a.y, acc[1]);
      acc[2] = fmaf(f, a.z, acc[2]); acc[3] = fmaf(f, a.w, acc[3]);
      acc[4] = fmaf(f, d.x, acc[4]); acc[5] = fmaf(f, d.y, acc[5]);
      acc[6] = fmaf(f, d.z, acc[6]); acc[7] = fmaf(f, d.w, acc[7]);
    }
  }

  float* op = out + (size_t)b * 1048576 + (c0 + c_l) * 8192 + (i0 + i_l) * 16 + th * 8;
  ((float4*)op)[0] = *(const float4*)(acc);
  ((float4*)op)[1] = *(const float4*)(acc + 4);
}

// ---------------------------------------------------------------------------
extern "C" void kernel_launch(void* const* d_in, const int* in_sizes, int n_in,
                              void* d_out, int out_size, void* d_ws, size_t ws_size,
                              hipStream_t stream) {
  const float* x  = (const float*)d_in[0];
  const float* Wq = (const float*)d_in[1];
  const float* Wk = (const float*)d_in[2];
  const float* S  = (const float*)d_in[3];
  const float* fw = (const float*)d_in[4];
  const float* fb = (const float*)d_in[5];
  float* out = (float*)d_out;

  // workspace: Qb 8MB | Kb 8MB | part 16MB | accA 4MB | st 1MB | fused 4MB | Wb 64KB
  ushort* Qb   = (ushort*)d_ws;
  ushort* Kb   = Qb + 4194304;
  ushort* part = Kb + 4194304;
  float* accA  = (float*)(part + 8388608);
  float* st    = accA + 1048576;
  float* fused = st + 262144;
  ushort* Wqb  = (ushort*)(fused + 1048576);
  ushort* Wkb  = Wqb + 16384;

  k_wconv <<<dim3(32),        256, 0, stream>>>(Wq, Wk, Wqb, Wkb);
  k_proj  <<<dim3(64, 4),     256, 0, stream>>>(x, Wqb, Wkb, Qb, Kb);
  k_scores<<<dim3(32, 8, 4),   64, 0, stream>>>(Qb, Kb, part);
  k_struct<<<dim3(512),       256, 0, stream>>>(S, st);
  k_reduce<<<dim3(1024),      256, 0, stream>>>(part, accA);
  k_fused <<<dim3(512, 4),    256, 0, stream>>>(accA, st, fw, fb, fused);
  k_agg   <<<dim3(32, 16, 4), 256, 0, stream>>>(fused, x, out);
}

// Round 4
// 184.105 us; speedup vs baseline: 3.0533x; 1.3272x over previous
//
#include <hip/hip_runtime.h>

// Problem constants
#define BB 4
#define CC 128
#define NN 512
#define TT 16
#define HH 4
#define DKK 32
// SCALE = sqrt(DK) = sqrt(32);  1/SCALE:
#define INV_SCALE 0.17677669529663687f

typedef __attribute__((ext_vector_type(8))) short bf16x8;
typedef __attribute__((ext_vector_type(4))) float f32x4;

// pack two floats to bf16 pair (RNE)
__device__ __forceinline__ unsigned int pk2bf(float a, float b) {
  unsigned int ua = __float_as_uint(a);
  ua = (ua + 0x7FFFu + ((ua >> 16) & 1u)) >> 16;
  unsigned int ub = __float_as_uint(b);
  ub = (ub + 0x7FFFu + ((ub >> 16) & 1u)) >> 16;
  return ua | (ub << 16);
}

// single float -> bf16 (RNE)
__device__ __forceinline__ ushort cv1(float f) {
  unsigned int u = __float_as_uint(f);
  return (ushort)((u + 0x7FFFu + ((u >> 16) & 1u)) >> 16);
}

// fast pack (round-half-up): v_add x2 + v_perm
__device__ __forceinline__ unsigned int pkfast(float a, float b) {
  unsigned int au = __float_as_uint(a) + 0x8000u;
  unsigned int bu = __float_as_uint(b) + 0x8000u;
  return __builtin_amdgcn_perm(bu, au, 0x07060302u);
}

// ---------------------------------------------------------------------------
// Kernel 0: W -> bf16
// ---------------------------------------------------------------------------
__global__ __launch_bounds__(256) void k_wconv(const float* __restrict__ Wq,
                                               const float* __restrict__ Wk,
                                               ushort* __restrict__ Wqb,
                                               ushort* __restrict__ Wkb) {
  const int gid = blockIdx.x * 256 + threadIdx.x;
  const int i = gid * 4;
  const float* src = (i < 16384) ? (Wq + i) : (Wk + i - 16384);
  ushort* dst = (i < 16384) ? (Wqb + i) : (Wkb + i - 16384);
  float4 v = *(const float4*)src;
  uint2 u;
  u.x = pk2bf(v.x, v.y);
  u.y = pk2bf(v.z, v.w);
  *(uint2*)dst = u;
}

// ---------------------------------------------------------------------------
// Kernel 1: MFMA Q/K projection -> bf16 (unchanged from round 3)
// ---------------------------------------------------------------------------
__global__ __launch_bounds__(256) void k_proj(const float* __restrict__ x,
                                              const ushort* __restrict__ Wqb,
                                              const ushort* __restrict__ Wkb,
                                              ushort* __restrict__ Qb,
                                              ushort* __restrict__ Kb) {
  __shared__ float xl[128 * 128];
  const int b = blockIdx.y;
  const int nt0 = blockIdx.x * 128;
  const int tid = threadIdx.x;
  const int w = tid >> 6, lane = tid & 63;
  const int lm = lane & 15, quad = lane >> 4;

  const float* xb = x + (size_t)b * 1048576 + nt0;
#pragma unroll
  for (int L = tid * 4; L < 16384; L += 1024) {
    int c = L >> 7, j = L & 127;
    *(float4*)(xl + L) = *(const float4*)(xb + c * 8192 + j);
  }

  const int o0 = w * 32;
  bf16x8 aq[2][4], ak[2][4];
#pragma unroll
  for (int ot = 0; ot < 2; ++ot)
#pragma unroll
    for (int kc = 0; kc < 4; ++kc) {
      int off = (o0 + ot * 16 + lm) * 128 + kc * 32 + quad * 8;
      aq[ot][kc] = *(const bf16x8*)(Wqb + off);
      ak[ot][kc] = *(const bf16x8*)(Wkb + off);
    }
  __syncthreads();

  const int nq = nt0 >> 4;
#pragma unroll 2
  for (int jt = 0; jt < 8; ++jt) {
    bf16x8 bfr[4];
#pragma unroll
    for (int kc = 0; kc < 4; ++kc) {
      const float* sp = xl + (kc * 32 + quad * 8) * 128 + jt * 16 + lm;
      float f0 = sp[0],   f1 = sp[128], f2 = sp[256], f3 = sp[384];
      float f4 = sp[512], f5 = sp[640], f6 = sp[768], f7 = sp[896];
      uint4 u;
      u.x = pkfast(f0, f1);
      u.y = pkfast(f2, f3);
      u.z = pkfast(f4, f5);
      u.w = pkfast(f6, f7);
      union { uint4 u; bf16x8 v; } cv;
      cv.u = u;
      bfr[kc] = cv.v;
    }

    f32x4 accq0 = {0,0,0,0}, accq1 = {0,0,0,0};
    f32x4 acck0 = {0,0,0,0}, acck1 = {0,0,0,0};
#pragma unroll
    for (int kc = 0; kc < 4; ++kc) {
      accq0 = __builtin_amdgcn_mfma_f32_16x16x32_bf16(aq[0][kc], bfr[kc], accq0, 0, 0, 0);
      accq1 = __builtin_amdgcn_mfma_f32_16x16x32_bf16(aq[1][kc], bfr[kc], accq1, 0, 0, 0);
      acck0 = __builtin_amdgcn_mfma_f32_16x16x32_bf16(ak[0][kc], bfr[kc], acck0, 0, 0, 0);
      acck1 = __builtin_amdgcn_mfma_f32_16x16x32_bf16(ak[1][kc], bfr[kc], acck1, 0, 0, 0);
    }

    const size_t base = (size_t)b * 1048576 + (size_t)lm * 65536 + w * 16384 +
                        (size_t)(nq + jt) * 32 + quad * 4;
    uint2 uq0, uq1, uk0, uk1;
    uq0.x = pk2bf(accq0[0], accq0[1]); uq0.y = pk2bf(accq0[2], accq0[3]);
    uq1.x = pk2bf(accq1[0], accq1[1]); uq1.y = pk2bf(accq1[2], accq1[3]);
    uk0.x = pk2bf(acck0[0], acck0[1]); uk0.y = pk2bf(acck0[2], acck0[3]);
    uk1.x = pk2bf(acck1[0], acck1[1]); uk1.y = pk2bf(acck1[2], acck1[3]);
    *(uint2*)(Qb + base)      = uq0;
    *(uint2*)(Qb + base + 16) = uq1;
    *(uint2*)(Kb + base)      = uk0;
    *(uint2*)(Kb + base + 16) = uk1;
  }
}

// ---------------------------------------------------------------------------
// Kernel 2: MFMA scores + softmax + partial mean (unchanged)
// ---------------------------------------------------------------------------
__global__ __launch_bounds__(64) void k_scores(const ushort* __restrict__ Qb,
                                               const ushort* __restrict__ Kb,
                                               ushort* __restrict__ part) {
  __shared__ float SH[16 * 516];
  const int strip = blockIdx.x, g = blockIdx.y, b = blockIdx.z;
  const int lane = threadIdx.x;
  const int lm = lane & 15, quad = lane >> 4;
  const int n0 = strip * 16;
  const int d0 = quad * 8;
  const int r2 = lane >> 2, cb2 = (lane & 3) * 4;
  const int rsel = r2 & 3;

  float acc[128];
#pragma unroll
  for (int i = 0; i < 128; ++i) acc[i] = 0.f;

  for (int pi = 0; pi < 8; ++pi) {
    const int p = (g << 3) + pi, t = p >> 2, h = p & 3;
    const size_t base = (size_t)(((b * 16 + t) * 4 + h)) * 16384;
    bf16x8 afrag = *(const bf16x8*)(Qb + base + (size_t)(n0 + lm) * 32 + d0);
    float rp0 = 0.f, rp1 = 0.f, rp2 = 0.f, rp3 = 0.f;
    bf16x8 bfrag = *(const bf16x8*)(Kb + base + (size_t)lm * 32 + d0);
#pragma unroll 4
    for (int ct = 0; ct < 32; ++ct) {
      bf16x8 curb = bfrag;
      if (ct < 31)
        bfrag = *(const bf16x8*)(Kb + base + (size_t)((ct + 1) * 16 + lm) * 32 + d0);
      f32x4 z = {0.f, 0.f, 0.f, 0.f};
      f32x4 dv = __builtin_amdgcn_mfma_f32_16x16x32_bf16(afrag, curb, z, 0, 0, 0);
      float e0 = __expf(dv[0] * INV_SCALE);
      float e1 = __expf(dv[1] * INV_SCALE);
      float e2 = __expf(dv[2] * INV_SCALE);
      float e3 = __expf(dv[3] * INV_SCALE);
      float* sp = SH + (quad * 4) * 516 + ct * 16 + lm;
      sp[0] = e0; sp[516] = e1; sp[1032] = e2; sp[1548] = e3;
      rp0 += e0; rp1 += e1; rp2 += e2; rp3 += e3;
    }
#pragma unroll
    for (int m = 1; m < 16; m <<= 1) {
      rp0 += __shfl_xor(rp0, m);
      rp1 += __shfl_xor(rp1, m);
      rp2 += __shfl_xor(rp2, m);
      rp3 += __shfl_xor(rp3, m);
    }
    float rs = (rsel == 0) ? rp0 : (rsel == 1) ? rp1 : (rsel == 2) ? rp2 : rp3;
    float inv = 1.0f / rs;
    __builtin_amdgcn_s_waitcnt(0xC07F);
#pragma unroll
    for (int k = 0; k < 32; ++k) {
      f32x4 v = *(const f32x4*)(SH + r2 * 516 + cb2 + k * 16);
      acc[k * 4 + 0] = fmaf(v[0], inv, acc[k * 4 + 0]);
      acc[k * 4 + 1] = fmaf(v[1], inv, acc[k * 4 + 1]);
      acc[k * 4 + 2] = fmaf(v[2], inv, acc[k * 4 + 2]);
      acc[k * 4 + 3] = fmaf(v[3], inv, acc[k * 4 + 3]);
    }
  }

  ushort* po = part + ((size_t)((g * 4 + b) * 512 + n0 + r2)) * 512 + cb2;
#pragma unroll
  for (int k = 0; k < 32; ++k) {
    uint2 u;
    u.x = pk2bf(acc[k * 4 + 0], acc[k * 4 + 1]);
    u.y = pk2bf(acc[k * 4 + 2], acc[k * 4 + 3]);
    *(uint2*)(po + k * 16) = u;
  }
}

// ---------------------------------------------------------------------------
// Kernel 2b: reduce 8 bf16 partials -> accA fp32
// ---------------------------------------------------------------------------
__global__ __launch_bounds__(256) void k_reduce(const ushort* __restrict__ part,
                                                float* __restrict__ accA) {
  const int gid = blockIdx.x * 256 + threadIdx.x;
  const size_t idx = (size_t)gid * 4;
  float s0 = 0.f, s1 = 0.f, s2 = 0.f, s3 = 0.f;
#pragma unroll
  for (int g = 0; g < 8; ++g) {
    ushort4 v = *(const ushort4*)(part + (size_t)g * 1048576 + idx);
    s0 += __uint_as_float((unsigned int)v.x << 16);
    s1 += __uint_as_float((unsigned int)v.y << 16);
    s2 += __uint_as_float((unsigned int)v.z << 16);
    s3 += __uint_as_float((unsigned int)v.w << 16);
  }
  float4 o = make_float4(s0, s1, s2, s3);
  *(float4*)(accA + idx) = o;
}

// ---------------------------------------------------------------------------
// Kernel 2c: in-place symmetrize M <- M + M^T for 512x512 fp32 matrices.
// grid (36 tile-pairs, 5 matrices): z=0..3 accA[b], z=4 st.
// ---------------------------------------------------------------------------
__global__ __launch_bounds__(256) void k_sym(float* __restrict__ accA,
                                             float* __restrict__ st) {
  __shared__ float L1[64 * 68];
  __shared__ float L2[64 * 68];
  const int z = blockIdx.y;
  float* M = (z < 4) ? (accA + (size_t)z * 262144) : st;
  int rem = blockIdx.x, ti = 0;
  for (;;) { int cnt = 8 - ti; if (rem < cnt) break; rem -= cnt; ++ti; }
  const int tj = ti + rem;
  const bool diag = (ti == tj);
  const int tid = threadIdx.x;

#pragma unroll
  for (int it = 0; it < 4; ++it) {
    int L = tid * 4 + it * 1024;
    int r = L >> 6, c = L & 63;
    *(float4*)(L1 + r * 68 + c) = *(const float4*)(M + (ti * 64 + r) * 512 + tj * 64 + c);
    if (!diag)
      *(float4*)(L2 + r * 68 + c) = *(const float4*)(M + (tj * 64 + r) * 512 + ti * 64 + c);
  }
  __syncthreads();

  const float* LT = diag ? L1 : L2;
#pragma unroll
  for (int it = 0; it < 4; ++it) {
    int L = tid * 4 + it * 1024;
    int r = L >> 6, c = L & 63;
    float4 o1;
    o1.x = L1[r * 68 + c + 0] + LT[(c + 0) * 68 + r];
    o1.y = L1[r * 68 + c + 1] + LT[(c + 1) * 68 + r];
    o1.z = L1[r * 68 + c + 2] + LT[(c + 2) * 68 + r];
    o1.w = L1[r * 68 + c + 3] + LT[(c + 3) * 68 + r];
    *(float4*)(M + (ti * 64 + r) * 512 + tj * 64 + c) = o1;
    if (!diag) {
      float4 o2;
      o2.x = L2[r * 68 + c + 0] + L1[(c + 0) * 68 + r];
      o2.y = L2[r * 68 + c + 1] + L1[(c + 1) * 68 + r];
      o2.z = L2[r * 68 + c + 2] + L1[(c + 2) * 68 + r];
      o2.w = L2[r * 68 + c + 3] + L1[(c + 3) * 68 + r];
      *(float4*)(M + (tj * 64 + r) * 512 + ti * 64 + c) = o2;
    }
  }
}

// ---------------------------------------------------------------------------
// Kernel 2d: x[b,c,j,t] fp32 -> xtb[b,c,t,j] bf16 (transposed per (b,c))
// ---------------------------------------------------------------------------
__global__ __launch_bounds__(256) void k_xconv(const float* __restrict__ x,
                                               ushort* __restrict__ xtb) {
  __shared__ ushort xs[16 * 520];
  const int c = blockIdx.x, b = blockIdx.y;
  const int tid = threadIdx.x;
  const float* in = x + ((size_t)b * 128 + c) * 8192;
  ushort* outp = xtb + ((size_t)b * 128 + c) * 8192;

#pragma unroll
  for (int it = 0; it < 8; ++it) {
    int idx = (tid + it * 256) * 4;
    int j = idx >> 4, t0 = idx & 15;
    float4 v = *(const float4*)(in + idx);
    xs[(t0 + 0) * 520 + j] = cv1(v.x);
    xs[(t0 + 1) * 520 + j] = cv1(v.y);
    xs[(t0 + 2) * 520 + j] = cv1(v.z);
    xs[(t0 + 3) * 520 + j] = cv1(v.w);
  }
  __syncthreads();
#pragma unroll
  for (int it = 0; it < 4; ++it) {
    int u = (tid + it * 256) * 8;
    int t = u >> 9, j0 = u & 511;
    *(uint4*)(outp + u) = *(const uint4*)(xs + t * 520 + j0);
  }
}

// ---------------------------------------------------------------------------
// Block reductions
// ---------------------------------------------------------------------------
__device__ __forceinline__ float blk_max(float v, float* red, int tid) {
#pragma unroll
  for (int off = 32; off > 0; off >>= 1) v = fmaxf(v, __shfl_xor(v, off, 64));
  if ((tid & 63) == 0) red[tid >> 6] = v;
  __syncthreads();
  v = fmaxf(fmaxf(red[0], red[1]), fmaxf(red[2], red[3]));
  __syncthreads();
  return v;
}
__device__ __forceinline__ float blk_sum(float v, float* red, int tid) {
#pragma unroll
  for (int off = 32; off > 0; off >>= 1) v += __shfl_xor(v, off, 64);
  if ((tid & 63) == 0) red[tid >> 6] = v;
  __syncthreads();
  v = (red[0] + red[1]) + (red[2] + red[3]);
  __syncthreads();
  return v;
}

// Kernel 3a: att_struct = softmax(structural, axis=-1)
__global__ __launch_bounds__(256) void k_struct(const float* __restrict__ S,
                                                float* __restrict__ st) {
  __shared__ float red[4];
  const int i = blockIdx.x, tid = threadIdx.x;
  float s0 = S[i * 512 + tid], s1 = S[i * 512 + tid + 256];
  float m = blk_max(fmaxf(s0, s1), red, tid);
  float e0 = __expf(s0 - m), e1 = __expf(s1 - m);
  float sum = blk_sum(e0 + e1, red, tid);
  float inv = 1.0f / sum;
  st[i * 512 + tid] = e0 * inv;
  st[i * 512 + tid + 256] = e1 * inv;
}

// Kernel 3b: fused row softmax from symmetrized inputs -> bf16
// accA, st hold (M + M^T) after k_sym.
__global__ __launch_bounds__(256) void k_fused(const float* __restrict__ accA,
                                               const float* __restrict__ st,
                                               const float* __restrict__ fw,
                                               const float* __restrict__ fb,
                                               ushort* __restrict__ fusedb) {
  __shared__ float red[4];
  const int i = blockIdx.x, b = blockIdx.y, tid = threadIdx.x;
  const float w0s = fw[0] * (0.5f / 64.f);
  const float w1s = fw[1] * 0.5f;
  const float bias = fb[0];
  const float* A = accA + (size_t)b * 262144 + (size_t)i * 512;
  const float* S = st + (size_t)i * 512;
  float2 a2 = *(const float2*)(A + tid * 2);
  float2 s2 = *(const float2*)(S + tid * 2);
  float l0 = fmaf(w0s, a2.x, fmaf(w1s, s2.x, bias));
  float l1 = fmaf(w0s, a2.y, fmaf(w1s, s2.y, bias));
  float m = blk_max(fmaxf(l0, l1), red, tid);
  float e0 = __expf(l0 - m), e1 = __expf(l1 - m);
  float sum = blk_sum(e0 + e1, red, tid);
  float inv = 1.0f / sum;
  *(unsigned int*)(fusedb + ((size_t)(b * 512 + i)) * 512 + tid * 2) =
      pk2bf(e0 * inv, e1 * inv);
}

// ---------------------------------------------------------------------------
// Kernel 4: MFMA aggregation. out[b,c,i,t] = sum_j fusedb[b,i,j] * xtb[b,c,t,j]
// grid (16 c-groups of 8, 8 i-tiles of 64, 4 b), 256 threads (4 waves).
// Wave w: i-strip i0+w*16, holds all 16 A-frags (K=512) in regs.
// ---------------------------------------------------------------------------
__global__ __launch_bounds__(256) void k_agg(const ushort* __restrict__ fusedb,
                                             const ushort* __restrict__ xtb,
                                             float* __restrict__ out) {
  __shared__ ushort xs[16 * 520];  // 16 t-rows, stride 520 (pad 16B)
  const int cg = blockIdx.x;       // 0..15 -> c base cg*8
  const int i0 = blockIdx.y * 64;
  const int b = blockIdx.z;
  const int tid = threadIdx.x, w = tid >> 6, lane = tid & 63;
  const int lm = lane & 15, quad = lane >> 4;

  // A fragments: fusedb[b, i0+w*16+lm, kk*32 + quad*8 .. +7]
  const ushort* fr = fusedb + ((size_t)(b * 512 + i0 + w * 16 + lm)) * 512 + quad * 8;
  bf16x8 af[16];
#pragma unroll
  for (int kk = 0; kk < 16; ++kk) af[kk] = *(const bf16x8*)(fr + kk * 32);

  const ushort* xg = xtb + ((size_t)b * 128 + cg * 8) * 8192;
  uint4 rg[4];
#pragma unroll
  for (int it = 0; it < 4; ++it) rg[it] = *(const uint4*)(xg + (tid + it * 256) * 8);

  for (int c = 0; c < 8; ++c) {
#pragma unroll
    for (int it = 0; it < 4; ++it) {
      int u = (tid + it * 256) * 8;
      int t = u >> 9, j0 = u & 511;
      *(uint4*)(xs + t * 520 + j0) = rg[it];
    }
    __syncthreads();
    if (c < 7) {
      const ushort* xg2 = xg + (size_t)(c + 1) * 8192;
#pragma unroll
      for (int it = 0; it < 4; ++it) rg[it] = *(const uint4*)(xg2 + (tid + it * 256) * 8);
    }
    f32x4 acc = {0.f, 0.f, 0.f, 0.f};
#pragma unroll
    for (int kk = 0; kk < 16; ++kk) {
      bf16x8 bf = *(const bf16x8*)(xs + lm * 520 + kk * 32 + quad * 8);
      acc = __builtin_amdgcn_mfma_f32_16x16x32_bf16(af[kk], bf, acc, 0, 0, 0);
    }
    float* op = out + (size_t)b * 1048576 + (size_t)(cg * 8 + c) * 8192 +
                (size_t)(i0 + w * 16 + quad * 4) * 16 + lm;
    op[0]  = acc[0];
    op[16] = acc[1];
    op[32] = acc[2];
    op[48] = acc[3];
    __syncthreads();
  }
}

// ---------------------------------------------------------------------------
extern "C" void kernel_launch(void* const* d_in, const int* in_sizes, int n_in,
                              void* d_out, int out_size, void* d_ws, size_t ws_size,
                              hipStream_t stream) {
  const float* x  = (const float*)d_in[0];
  const float* Wq = (const float*)d_in[1];
  const float* Wk = (const float*)d_in[2];
  const float* S  = (const float*)d_in[3];
  const float* fw = (const float*)d_in[4];
  const float* fb = (const float*)d_in[5];
  float* out = (float*)d_out;

  // workspace layout (39.1 MB):
  //   [Qb 8MB | Kb 8MB | part 16MB]  <- overlaid by xtb (32MB) after k_reduce
  //   accA 4MB | st 1MB | fusedb 2MB | Wqb/Wkb 64KB
  ushort* Qb   = (ushort*)d_ws;
  ushort* Kb   = Qb + 4194304;
  ushort* part = Kb + 4194304;
  ushort* xtb  = (ushort*)d_ws;  // overlay, written by k_xconv after Qb/Kb/part dead
  float* accA  = (float*)d_ws + 8388608;
  float* st    = accA + 1048576;
  ushort* fusedb = (ushort*)(st + 262144);
  ushort* Wqb  = fusedb + 1048576;
  ushort* Wkb  = Wqb + 16384;

  k_wconv <<<dim3(32),        256, 0, stream>>>(Wq, Wk, Wqb, Wkb);
  k_proj  <<<dim3(64, 4),     256, 0, stream>>>(x, Wqb, Wkb, Qb, Kb);
  k_scores<<<dim3(32, 8, 4),   64, 0, stream>>>(Qb, Kb, part);
  k_struct<<<dim3(512),       256, 0, stream>>>(S, st);
  k_reduce<<<dim3(1024),      256, 0, stream>>>(part, accA);
  k_sym   <<<dim3(36, 5),     256, 0, stream>>>(accA, st);
  k_xconv <<<dim3(128, 4),    256, 0, stream>>>(x, xtb);
  k_fused <<<dim3(512, 4),    256, 0, stream>>>(accA, st, fw, fb, fusedb);
  k_agg   <<<dim3(16, 8, 4),  256, 0, stream>>>(fusedb, xtb, out);
}

// Round 5
// 162.232 us; speedup vs baseline: 3.4649x; 1.1348x over previous
//
#include <hip/hip_runtime.h>

// Problem constants
#define BB 4
#define CC 128
#define NN 512
#define TT 16
#define HH 4
#define DKK 32
// SCALE = sqrt(DK) = sqrt(32);  1/SCALE:
#define INV_SCALE 0.17677669529663687f

typedef __attribute__((ext_vector_type(8))) short bf16x8;
typedef __attribute__((ext_vector_type(4))) float f32x4;

// pack two floats to bf16 pair (RNE)
__device__ __forceinline__ unsigned int pk2bf(float a, float b) {
  unsigned int ua = __float_as_uint(a);
  ua = (ua + 0x7FFFu + ((ua >> 16) & 1u)) >> 16;
  unsigned int ub = __float_as_uint(b);
  ub = (ub + 0x7FFFu + ((ub >> 16) & 1u)) >> 16;
  return ua | (ub << 16);
}

// single float -> bf16 (RNE)
__device__ __forceinline__ ushort cv1(float f) {
  unsigned int u = __float_as_uint(f);
  return (ushort)((u + 0x7FFFu + ((u >> 16) & 1u)) >> 16);
}

// fast pack (round-half-up): v_add x2 + v_perm
__device__ __forceinline__ unsigned int pkfast(float a, float b) {
  unsigned int au = __float_as_uint(a) + 0x8000u;
  unsigned int bu = __float_as_uint(b) + 0x8000u;
  return __builtin_amdgcn_perm(bu, au, 0x07060302u);
}

// ---------------------------------------------------------------------------
// Kernel 0: W -> bf16
// ---------------------------------------------------------------------------
__global__ __launch_bounds__(256) void k_wconv(const float* __restrict__ Wq,
                                               const float* __restrict__ Wk,
                                               ushort* __restrict__ Wqb,
                                               ushort* __restrict__ Wkb) {
  const int gid = blockIdx.x * 256 + threadIdx.x;
  const int i = gid * 4;
  const float* src = (i < 16384) ? (Wq + i) : (Wk + i - 16384);
  ushort* dst = (i < 16384) ? (Wqb + i) : (Wkb + i - 16384);
  float4 v = *(const float4*)src;
  uint2 u;
  u.x = pk2bf(v.x, v.y);
  u.y = pk2bf(v.z, v.w);
  *(uint2*)dst = u;
}

// ---------------------------------------------------------------------------
// Kernel 1: MFMA Q/K projection -> bf16 (unchanged)
// ---------------------------------------------------------------------------
__global__ __launch_bounds__(256) void k_proj(const float* __restrict__ x,
                                              const ushort* __restrict__ Wqb,
                                              const ushort* __restrict__ Wkb,
                                              ushort* __restrict__ Qb,
                                              ushort* __restrict__ Kb) {
  __shared__ float xl[128 * 128];
  const int b = blockIdx.y;
  const int nt0 = blockIdx.x * 128;
  const int tid = threadIdx.x;
  const int w = tid >> 6, lane = tid & 63;
  const int lm = lane & 15, quad = lane >> 4;

  const float* xb = x + (size_t)b * 1048576 + nt0;
#pragma unroll
  for (int L = tid * 4; L < 16384; L += 1024) {
    int c = L >> 7, j = L & 127;
    *(float4*)(xl + L) = *(const float4*)(xb + c * 8192 + j);
  }

  const int o0 = w * 32;
  bf16x8 aq[2][4], ak[2][4];
#pragma unroll
  for (int ot = 0; ot < 2; ++ot)
#pragma unroll
    for (int kc = 0; kc < 4; ++kc) {
      int off = (o0 + ot * 16 + lm) * 128 + kc * 32 + quad * 8;
      aq[ot][kc] = *(const bf16x8*)(Wqb + off);
      ak[ot][kc] = *(const bf16x8*)(Wkb + off);
    }
  __syncthreads();

  const int nq = nt0 >> 4;
#pragma unroll 2
  for (int jt = 0; jt < 8; ++jt) {
    bf16x8 bfr[4];
#pragma unroll
    for (int kc = 0; kc < 4; ++kc) {
      const float* sp = xl + (kc * 32 + quad * 8) * 128 + jt * 16 + lm;
      float f0 = sp[0],   f1 = sp[128], f2 = sp[256], f3 = sp[384];
      float f4 = sp[512], f5 = sp[640], f6 = sp[768], f7 = sp[896];
      uint4 u;
      u.x = pkfast(f0, f1);
      u.y = pkfast(f2, f3);
      u.z = pkfast(f4, f5);
      u.w = pkfast(f6, f7);
      union { uint4 u; bf16x8 v; } cv;
      cv.u = u;
      bfr[kc] = cv.v;
    }

    f32x4 accq0 = {0,0,0,0}, accq1 = {0,0,0,0};
    f32x4 acck0 = {0,0,0,0}, acck1 = {0,0,0,0};
#pragma unroll
    for (int kc = 0; kc < 4; ++kc) {
      accq0 = __builtin_amdgcn_mfma_f32_16x16x32_bf16(aq[0][kc], bfr[kc], accq0, 0, 0, 0);
      accq1 = __builtin_amdgcn_mfma_f32_16x16x32_bf16(aq[1][kc], bfr[kc], accq1, 0, 0, 0);
      acck0 = __builtin_amdgcn_mfma_f32_16x16x32_bf16(ak[0][kc], bfr[kc], acck0, 0, 0, 0);
      acck1 = __builtin_amdgcn_mfma_f32_16x16x32_bf16(ak[1][kc], bfr[kc], acck1, 0, 0, 0);
    }

    const size_t base = (size_t)b * 1048576 + (size_t)lm * 65536 + w * 16384 +
                        (size_t)(nq + jt) * 32 + quad * 4;
    uint2 uq0, uq1, uk0, uk1;
    uq0.x = pk2bf(accq0[0], accq0[1]); uq0.y = pk2bf(accq0[2], accq0[3]);
    uq1.x = pk2bf(accq1[0], accq1[1]); uq1.y = pk2bf(accq1[2], accq1[3]);
    uk0.x = pk2bf(acck0[0], acck0[1]); uk0.y = pk2bf(acck0[2], acck0[3]);
    uk1.x = pk2bf(acck1[0], acck1[1]); uk1.y = pk2bf(acck1[2], acck1[3]);
    *(uint2*)(Qb + base)      = uq0;
    *(uint2*)(Qb + base + 16) = uq1;
    *(uint2*)(Kb + base)      = uk0;
    *(uint2*)(Kb + base + 16) = uk1;
  }
}

// ---------------------------------------------------------------------------
// Kernel 2: MFMA scores + softmax + partial mean over (t,h). REWRITTEN.
// Grid (32 strips, 8 groups, 4 b), block = 256 threads (4 waves).
// Wave w owns cols w*128..w*128+127 of a 16-row strip. Softmax accumulation
// stays in MFMA D-layout registers; rowsums cross waves via tiny LDS;
// the 33KB LDS strip is used only once (epilogue transpose for stores).
// ---------------------------------------------------------------------------
__global__ __launch_bounds__(256, 4) void k_scores(const ushort* __restrict__ Qb,
                                                   const ushort* __restrict__ Kb,
                                                   ushort* __restrict__ part) {
  __shared__ float SH[16 * 516];   // epilogue transpose only
  __shared__ float red[2][4][16];  // [pair parity][wave][row]
  const int strip = blockIdx.x, g = blockIdx.y, b = blockIdx.z;
  const int tid = threadIdx.x;
  const int w = tid >> 6, lane = tid & 63;
  const int lm = lane & 15, quad = lane >> 4;
  const int n0 = strip * 16;
  const int wcol0 = w * 128;

  float acc[32];
#pragma unroll
  for (int i = 0; i < 32; ++i) acc[i] = 0.f;

  for (int pi = 0; pi < 8; ++pi) {
    const int p = (g << 3) + pi;
    const size_t base = (size_t)((b * 16 + (p >> 2)) * 4 + (p & 3)) * 16384;
    bf16x8 afrag = *(const bf16x8*)(Qb + base + (size_t)(n0 + lm) * 32 + quad * 8);
    bf16x8 bfr[8];
#pragma unroll
    for (int ct = 0; ct < 8; ++ct)
      bfr[ct] = *(const bf16x8*)(Kb + base + (size_t)(wcol0 + ct * 16 + lm) * 32 + quad * 8);

    f32x4 d[8];
#pragma unroll
    for (int ct = 0; ct < 8; ++ct) {
      f32x4 z = {0.f, 0.f, 0.f, 0.f};
      d[ct] = __builtin_amdgcn_mfma_f32_16x16x32_bf16(afrag, bfr[ct], z, 0, 0, 0);
    }

    // exp in D-layout: lane's d[ct][r] is row quad*4+r, col wcol0+ct*16+lm
    float cur[32];
    float rp0 = 0.f, rp1 = 0.f, rp2 = 0.f, rp3 = 0.f;
#pragma unroll
    for (int ct = 0; ct < 8; ++ct) {
      float e0 = __expf(d[ct][0] * INV_SCALE);
      float e1 = __expf(d[ct][1] * INV_SCALE);
      float e2 = __expf(d[ct][2] * INV_SCALE);
      float e3 = __expf(d[ct][3] * INV_SCALE);
      cur[ct * 4 + 0] = e0; cur[ct * 4 + 1] = e1;
      cur[ct * 4 + 2] = e2; cur[ct * 4 + 3] = e3;
      rp0 += e0; rp1 += e1; rp2 += e2; rp3 += e3;
    }
    // reduce over the 16 lanes of this quad-group (cols of this wave)
#pragma unroll
    for (int m = 1; m < 16; m <<= 1) {
      rp0 += __shfl_xor(rp0, m);
      rp1 += __shfl_xor(rp1, m);
      rp2 += __shfl_xor(rp2, m);
      rp3 += __shfl_xor(rp3, m);
    }
    if (lm == 0) {
      red[pi & 1][w][quad * 4 + 0] = rp0;
      red[pi & 1][w][quad * 4 + 1] = rp1;
      red[pi & 1][w][quad * 4 + 2] = rp2;
      red[pi & 1][w][quad * 4 + 3] = rp3;
    }
    __syncthreads();
    // total rowsum across 4 waves (broadcast reads), then accumulate
#pragma unroll
    for (int r = 0; r < 4; ++r) {
      float rs = red[pi & 1][0][quad * 4 + r] + red[pi & 1][1][quad * 4 + r] +
                 red[pi & 1][2][quad * 4 + r] + red[pi & 1][3][quad * 4 + r];
      float inv = 1.0f / rs;
#pragma unroll
      for (int ct = 0; ct < 8; ++ct)
        acc[ct * 4 + r] = fmaf(cur[ct * 4 + r], inv, acc[ct * 4 + r]);
    }
  }

  // epilogue: transpose via LDS for coalesced bf16 stores
#pragma unroll
  for (int ct = 0; ct < 8; ++ct) {
#pragma unroll
    for (int r = 0; r < 4; ++r)
      SH[(quad * 4 + r) * 516 + wcol0 + ct * 16 + lm] = acc[ct * 4 + r];
  }
  __syncthreads();
  const int row = tid >> 4, colb = (tid & 15) * 4;
  ushort* po = part + ((size_t)((g * 4 + b) * 512 + n0 + row)) * 512 + colb;
#pragma unroll
  for (int k = 0; k < 8; ++k) {
    f32x4 v = *(const f32x4*)(SH + row * 516 + colb + k * 64);
    uint2 u;
    u.x = pk2bf(v[0], v[1]);
    u.y = pk2bf(v[2], v[3]);
    *(uint2*)(po + k * 64) = u;
  }
}

// ---------------------------------------------------------------------------
// Kernel 2b: reduce 8 bf16 partials -> accA fp32
// ---------------------------------------------------------------------------
__global__ __launch_bounds__(256) void k_reduce(const ushort* __restrict__ part,
                                                float* __restrict__ accA) {
  const int gid = blockIdx.x * 256 + threadIdx.x;
  const size_t idx = (size_t)gid * 4;
  float s0 = 0.f, s1 = 0.f, s2 = 0.f, s3 = 0.f;
#pragma unroll
  for (int g = 0; g < 8; ++g) {
    ushort4 v = *(const ushort4*)(part + (size_t)g * 1048576 + idx);
    s0 += __uint_as_float((unsigned int)v.x << 16);
    s1 += __uint_as_float((unsigned int)v.y << 16);
    s2 += __uint_as_float((unsigned int)v.z << 16);
    s3 += __uint_as_float((unsigned int)v.w << 16);
  }
  float4 o = make_float4(s0, s1, s2, s3);
  *(float4*)(accA + idx) = o;
}

// ---------------------------------------------------------------------------
// Kernel 2c: in-place symmetrize M <- M + M^T (512x512 fp32); z=0..3 accA, z=4 st
// ---------------------------------------------------------------------------
__global__ __launch_bounds__(256) void k_sym(float* __restrict__ accA,
                                             float* __restrict__ st) {
  __shared__ float L1[64 * 68];
  __shared__ float L2[64 * 68];
  const int z = blockIdx.y;
  float* M = (z < 4) ? (accA + (size_t)z * 262144) : st;
  int rem = blockIdx.x, ti = 0;
  for (;;) { int cnt = 8 - ti; if (rem < cnt) break; rem -= cnt; ++ti; }
  const int tj = ti + rem;
  const bool diag = (ti == tj);
  const int tid = threadIdx.x;

#pragma unroll
  for (int it = 0; it < 4; ++it) {
    int L = tid * 4 + it * 1024;
    int r = L >> 6, c = L & 63;
    *(float4*)(L1 + r * 68 + c) = *(const float4*)(M + (ti * 64 + r) * 512 + tj * 64 + c);
    if (!diag)
      *(float4*)(L2 + r * 68 + c) = *(const float4*)(M + (tj * 64 + r) * 512 + ti * 64 + c);
  }
  __syncthreads();

  const float* LT = diag ? L1 : L2;
#pragma unroll
  for (int it = 0; it < 4; ++it) {
    int L = tid * 4 + it * 1024;
    int r = L >> 6, c = L & 63;
    float4 o1;
    o1.x = L1[r * 68 + c + 0] + LT[(c + 0) * 68 + r];
    o1.y = L1[r * 68 + c + 1] + LT[(c + 1) * 68 + r];
    o1.z = L1[r * 68 + c + 2] + LT[(c + 2) * 68 + r];
    o1.w = L1[r * 68 + c + 3] + LT[(c + 3) * 68 + r];
    *(float4*)(M + (ti * 64 + r) * 512 + tj * 64 + c) = o1;
    if (!diag) {
      float4 o2;
      o2.x = L2[r * 68 + c + 0] + L1[(c + 0) * 68 + r];
      o2.y = L2[r * 68 + c + 1] + L1[(c + 1) * 68 + r];
      o2.z = L2[r * 68 + c + 2] + L1[(c + 2) * 68 + r];
      o2.w = L2[r * 68 + c + 3] + L1[(c + 3) * 68 + r];
      *(float4*)(M + (tj * 64 + r) * 512 + ti * 64 + c) = o2;
    }
  }
}

// ---------------------------------------------------------------------------
// Kernel 2d: x[b,c,j,t] fp32 -> xtb[b,c,t,j] bf16
// ---------------------------------------------------------------------------
__global__ __launch_bounds__(256) void k_xconv(const float* __restrict__ x,
                                               ushort* __restrict__ xtb) {
  __shared__ ushort xs[16 * 520];
  const int c = blockIdx.x, b = blockIdx.y;
  const int tid = threadIdx.x;
  const float* in = x + ((size_t)b * 128 + c) * 8192;
  ushort* outp = xtb + ((size_t)b * 128 + c) * 8192;

#pragma unroll
  for (int it = 0; it < 8; ++it) {
    int idx = (tid + it * 256) * 4;
    int j = idx >> 4, t0 = idx & 15;
    float4 v = *(const float4*)(in + idx);
    xs[(t0 + 0) * 520 + j] = cv1(v.x);
    xs[(t0 + 1) * 520 + j] = cv1(v.y);
    xs[(t0 + 2) * 520 + j] = cv1(v.z);
    xs[(t0 + 3) * 520 + j] = cv1(v.w);
  }
  __syncthreads();
#pragma unroll
  for (int it = 0; it < 4; ++it) {
    int u = (tid + it * 256) * 8;
    int t = u >> 9, j0 = u & 511;
    *(uint4*)(outp + u) = *(const uint4*)(xs + t * 520 + j0);
  }
}

// ---------------------------------------------------------------------------
// Block reductions
// ---------------------------------------------------------------------------
__device__ __forceinline__ float blk_max(float v, float* red, int tid) {
#pragma unroll
  for (int off = 32; off > 0; off >>= 1) v = fmaxf(v, __shfl_xor(v, off, 64));
  if ((tid & 63) == 0) red[tid >> 6] = v;
  __syncthreads();
  v = fmaxf(fmaxf(red[0], red[1]), fmaxf(red[2], red[3]));
  __syncthreads();
  return v;
}
__device__ __forceinline__ float blk_sum(float v, float* red, int tid) {
#pragma unroll
  for (int off = 32; off > 0; off >>= 1) v += __shfl_xor(v, off, 64);
  if ((tid & 63) == 0) red[tid >> 6] = v;
  __syncthreads();
  v = (red[0] + red[1]) + (red[2] + red[3]);
  __syncthreads();
  return v;
}

// Kernel 3a: att_struct = softmax(structural, axis=-1)
__global__ __launch_bounds__(256) void k_struct(const float* __restrict__ S,
                                                float* __restrict__ st) {
  __shared__ float red[4];
  const int i = blockIdx.x, tid = threadIdx.x;
  float s0 = S[i * 512 + tid], s1 = S[i * 512 + tid + 256];
  float m = blk_max(fmaxf(s0, s1), red, tid);
  float e0 = __expf(s0 - m), e1 = __expf(s1 - m);
  float sum = blk_sum(e0 + e1, red, tid);
  float inv = 1.0f / sum;
  st[i * 512 + tid] = e0 * inv;
  st[i * 512 + tid + 256] = e1 * inv;
}

// Kernel 3b: fused row softmax from symmetrized inputs -> bf16
__global__ __launch_bounds__(256) void k_fused(const float* __restrict__ accA,
                                               const float* __restrict__ st,
                                               const float* __restrict__ fw,
                                               const float* __restrict__ fb,
                                               ushort* __restrict__ fusedb) {
  __shared__ float red[4];
  const int i = blockIdx.x, b = blockIdx.y, tid = threadIdx.x;
  const float w0s = fw[0] * (0.5f / 64.f);
  const float w1s = fw[1] * 0.5f;
  const float bias = fb[0];
  const float* A = accA + (size_t)b * 262144 + (size_t)i * 512;
  const float* S = st + (size_t)i * 512;
  float2 a2 = *(const float2*)(A + tid * 2);
  float2 s2 = *(const float2*)(S + tid * 2);
  float l0 = fmaf(w0s, a2.x, fmaf(w1s, s2.x, bias));
  float l1 = fmaf(w0s, a2.y, fmaf(w1s, s2.y, bias));
  float m = blk_max(fmaxf(l0, l1), red, tid);
  float e0 = __expf(l0 - m), e1 = __expf(l1 - m);
  float sum = blk_sum(e0 + e1, red, tid);
  float inv = 1.0f / sum;
  *(unsigned int*)(fusedb + ((size_t)(b * 512 + i)) * 512 + tid * 2) =
      pk2bf(e0 * inv, e1 * inv);
}

// ---------------------------------------------------------------------------
// Kernel 4: MFMA aggregation. out[b,c,i,t] = sum_j fusedb[b,i,j] * xtb[b,c,t,j]
// ---------------------------------------------------------------------------
__global__ __launch_bounds__(256) void k_agg(const ushort* __restrict__ fusedb,
                                             const ushort* __restrict__ xtb,
                                             float* __restrict__ out) {
  __shared__ ushort xs[16 * 520];
  const int cg = blockIdx.x;
  const int i0 = blockIdx.y * 64;
  const int b = blockIdx.z;
  const int tid = threadIdx.x, w = tid >> 6, lane = tid & 63;
  const int lm = lane & 15, quad = lane >> 4;

  const ushort* fr = fusedb + ((size_t)(b * 512 + i0 + w * 16 + lm)) * 512 + quad * 8;
  bf16x8 af[16];
#pragma unroll
  for (int kk = 0; kk < 16; ++kk) af[kk] = *(const bf16x8*)(fr + kk * 32);

  const ushort* xg = xtb + ((size_t)b * 128 + cg * 8) * 8192;
  uint4 rg[4];
#pragma unroll
  for (int it = 0; it < 4; ++it) rg[it] = *(const uint4*)(xg + (tid + it * 256) * 8);

  for (int c = 0; c < 8; ++c) {
#pragma unroll
    for (int it = 0; it < 4; ++it) {
      int u = (tid + it * 256) * 8;
      int t = u >> 9, j0 = u & 511;
      *(uint4*)(xs + t * 520 + j0) = rg[it];
    }
    __syncthreads();
    if (c < 7) {
      const ushort* xg2 = xg + (size_t)(c + 1) * 8192;
#pragma unroll
      for (int it = 0; it < 4; ++it) rg[it] = *(const uint4*)(xg2 + (tid + it * 256) * 8);
    }
    f32x4 acc = {0.f, 0.f, 0.f, 0.f};
#pragma unroll
    for (int kk = 0; kk < 16; ++kk) {
      bf16x8 bf = *(const bf16x8*)(xs + lm * 520 + kk * 32 + quad * 8);
      acc = __builtin_amdgcn_mfma_f32_16x16x32_bf16(af[kk], bf, acc, 0, 0, 0);
    }
    float* op = out + (size_t)b * 1048576 + (size_t)(cg * 8 + c) * 8192 +
                (size_t)(i0 + w * 16 + quad * 4) * 16 + lm;
    op[0]  = acc[0];
    op[16] = acc[1];
    op[32] = acc[2];
    op[48] = acc[3];
    __syncthreads();
  }
}

// ---------------------------------------------------------------------------
extern "C" void kernel_launch(void* const* d_in, const int* in_sizes, int n_in,
                              void* d_out, int out_size, void* d_ws, size_t ws_size,
                              hipStream_t stream) {
  const float* x  = (const float*)d_in[0];
  const float* Wq = (const float*)d_in[1];
  const float* Wk = (const float*)d_in[2];
  const float* S  = (const float*)d_in[3];
  const float* fw = (const float*)d_in[4];
  const float* fb = (const float*)d_in[5];
  float* out = (float*)d_out;

  ushort* Qb   = (ushort*)d_ws;
  ushort* Kb   = Qb + 4194304;
  ushort* part = Kb + 4194304;
  ushort* xtb  = (ushort*)d_ws;  // overlay after Qb/Kb/part dead
  float* accA  = (float*)d_ws + 8388608;
  float* st    = accA + 1048576;
  ushort* fusedb = (ushort*)(st + 262144);
  ushort* Wqb  = fusedb + 1048576;
  ushort* Wkb  = Wqb + 16384;

  k_wconv <<<dim3(32),        256, 0, stream>>>(Wq, Wk, Wqb, Wkb);
  k_proj  <<<dim3(64, 4),     256, 0, stream>>>(x, Wqb, Wkb, Qb, Kb);
  k_scores<<<dim3(32, 8, 4),  256, 0, stream>>>(Qb, Kb, part);
  k_struct<<<dim3(512),       256, 0, stream>>>(S, st);
  k_reduce<<<dim3(1024),      256, 0, stream>>>(part, accA);
  k_sym   <<<dim3(36, 5),     256, 0, stream>>>(accA, st);
  k_xconv <<<dim3(128, 4),    256, 0, stream>>>(x, xtb);
  k_fused <<<dim3(512, 4),    256, 0, stream>>>(accA, st, fw, fb, fusedb);
  k_agg   <<<dim3(16, 8, 4),  256, 0, stream>>>(fusedb, xtb, out);
}